// Round 2
// baseline (3041.221 us; speedup 1.0000x reference)
//
#include <hip/hip_runtime.h>
#include <hip/hip_bf16.h>

// SliceAttention on MI355X — round 2: fix workspace layout (TOKEN/NORM/OST
// sizes were wrong; atomics clobbered adjacent regions). Kernels unchanged.
// B=4 N=8192 H=1024 NH=16 D=M=64. Restructure: scores = x @ (wk_h @ xq_h^T),
// so stage-1 is ONE GEMM x[32768,1024] @ Wbig[1024,2048] -> [scores | xv].
// Softmax over m done in-place on scores; out_x overwrites dead xv columns.

#define NTOK 32768   // B*N
#define HH   1024
#define NHD  16
#define DD   64

// ---------------- Wbig builder: Acat columns (cols 0..1023) ----------------
__global__ __launch_bounds__(256) void k_acat(const float* __restrict__ w_kv,
                                              const float* __restrict__ xq,
                                              float* __restrict__ wbig) {
  int h = blockIdx.x >> 3, kt = blockIdx.x & 7, k0 = kt * 128;
  __shared__ float xqs[64 * 68];
  __shared__ float wks[128 * 68];
  int t = threadIdx.x;
  for (int j = 0; j < 16; ++j) {
    int idx = t + 256 * j; int m = idx >> 6, d = idx & 63;
    xqs[m * 68 + d] = xq[h * 4096 + idx];
  }
  for (int j = 0; j < 32; ++j) {
    int idx = t + 256 * j; int r = idx >> 6, c = idx & 63;
    wks[r * 68 + c] = w_kv[(k0 + r) * 2048 + h * 64 + c];
  }
  __syncthreads();
  int k = t >> 1, half = t & 1;
  float out[32];
  for (int mi = 0; mi < 32; ++mi) {
    int m = half * 32 + mi;
    float s = 0.f;
    #pragma unroll 8
    for (int d = 0; d < 64; ++d) s = fmaf(wks[k * 68 + d], xqs[m * 68 + d], s);
    out[mi] = s;
  }
  float* dst = &wbig[(k0 + k) * 2048 + h * 64 + half * 32];
  for (int mi = 0; mi < 32; mi += 4)
    *(float4*)(dst + mi) = make_float4(out[mi], out[mi + 1], out[mi + 2], out[mi + 3]);
}

// copy v-half of w_kv into Wbig cols 1024..2047
__global__ void k_copyv(const float* __restrict__ w_kv, float* __restrict__ wbig) {
  int idx4 = blockIdx.x * 256 + threadIdx.x;       // 262144 float4s
  int k = idx4 >> 8, j4 = idx4 & 255;
  int off = k * 2048 + 1024 + j4 * 4;
  *(float4*)(wbig + off) = *(const float4*)(w_kv + off);
}

// bias for the big GEMM: cols<1024 -> xq·b_kv(k-half); cols>=1024 -> b_kv(v-half)
__global__ void k_bias1(const float* __restrict__ xq, const float* __restrict__ b_kv,
                        float* __restrict__ bias1) {
  int j = blockIdx.x * 256 + threadIdx.x;
  if (j < 1024) {
    int h = j >> 6, m = j & 63;
    float s = 0.f;
    for (int d = 0; d < 64; ++d) s = fmaf(xq[h * 4096 + m * 64 + d], b_kv[h * 64 + d], s);
    bias1[j] = s;
  } else {
    bias1[j] = b_kv[j];
  }
}

// ---------------- temperature: T[bn][h] = 0.5 + softplus(x·w_temp + b_temp) ---
__global__ __launch_bounds__(256) void k_temp(const float* __restrict__ x,
                                              const float* __restrict__ w_temp,
                                              const float* __restrict__ b_temp,
                                              float* __restrict__ T) {
  __shared__ float xs[16 * 1028];
  int t = threadIdx.x;
  int bn0 = blockIdx.x * 16;
  for (int j = 0; j < 16; ++j) {
    int idx4 = t + 256 * j; int row = idx4 >> 8, c4 = (idx4 & 255) * 4;
    *(float4*)&xs[row * 1028 + c4] = *(const float4*)&x[(bn0 + row) * 1024 + c4];
  }
  __syncthreads();
  int tok = t >> 4, j = t & 15;
  float z = b_temp[j];
  for (int k = 0; k < 1024; ++k) z = fmaf(xs[tok * 1028 + k], w_temp[k * 16 + j], z);
  float sp = fmaxf(z, 0.f) + log1pf(expf(-fabsf(z)));
  T[(bn0 + tok) * 16 + j] = 0.5f + sp;
}

// ---------------- fp32 GEMM: C[M,N] = A[M,K]@B[K,N] + bias[N] ----------------
// 128x128 tile, BK=8, 256 thr, 8x8 per thread (cols tx*4 and 64+tx*4).
__global__ __launch_bounds__(256) void k_gemm(const float* __restrict__ A, int lda,
                                              const float* __restrict__ Bm, int ldb,
                                              const float* __restrict__ bias,
                                              float* __restrict__ C, int ldc, int K) {
  __shared__ float As[8 * 132];
  __shared__ float Bs[8 * 132];
  int t = threadIdx.x;
  int m0 = blockIdx.y * 128, n0 = blockIdx.x * 128;
  int ar = t >> 1, ac = (t & 1) * 4;
  int bk = t >> 5, bc = (t & 31) * 4;
  const float* Ag = A + (size_t)(m0 + ar) * lda + ac;
  const float* Bg = Bm + (size_t)bk * ldb + n0 + bc;
  int tx = t & 15, ty = t >> 4;
  float acc[8][8] = {};
  float4 a4 = *(const float4*)Ag;
  float4 b4 = *(const float4*)Bg;
  for (int kt = 0; kt < K; kt += 8) {
    __syncthreads();
    As[(ac + 0) * 132 + ar] = a4.x;
    As[(ac + 1) * 132 + ar] = a4.y;
    As[(ac + 2) * 132 + ar] = a4.z;
    As[(ac + 3) * 132 + ar] = a4.w;
    *(float4*)&Bs[bk * 132 + bc] = b4;
    __syncthreads();
    if (kt + 8 < K) {
      a4 = *(const float4*)(Ag + kt + 8);
      b4 = *(const float4*)(Bg + (size_t)(kt + 8) * ldb);
    }
    #pragma unroll
    for (int k = 0; k < 8; ++k) {
      float av[8], bv[8];
      *(float4*)&av[0] = *(float4*)&As[k * 132 + ty * 8];
      *(float4*)&av[4] = *(float4*)&As[k * 132 + ty * 8 + 4];
      *(float4*)&bv[0] = *(float4*)&Bs[k * 132 + tx * 4];
      *(float4*)&bv[4] = *(float4*)&Bs[k * 132 + 64 + tx * 4];
      #pragma unroll
      for (int i = 0; i < 8; ++i)
        #pragma unroll
        for (int j = 0; j < 8; ++j) acc[i][j] = fmaf(av[i], bv[j], acc[i][j]);
    }
  }
  float4 bb0 = *(const float4*)&bias[n0 + tx * 4];
  float4 bb1 = *(const float4*)&bias[n0 + 64 + tx * 4];
  #pragma unroll
  for (int i = 0; i < 8; ++i) {
    float* crow = C + (size_t)(m0 + ty * 8 + i) * ldc + n0;
    float4 o0 = make_float4(acc[i][0] + bb0.x, acc[i][1] + bb0.y,
                            acc[i][2] + bb0.z, acc[i][3] + bb0.w);
    float4 o1 = make_float4(acc[i][4] + bb1.x, acc[i][5] + bb1.y,
                            acc[i][6] + bb1.z, acc[i][7] + bb1.w);
    *(float4*)&crow[tx * 4] = o0;
    *(float4*)&crow[64 + tx * 4] = o1;
  }
}

// ------------- stage B: in-place softmax over m + token/norm accumulation ----
__global__ __launch_bounds__(256) void k_smax(float* __restrict__ S, const float* __restrict__ T,
                                              float* __restrict__ token, float* __restrict__ norm) {
  int pair = blockIdx.x >> 3, chunk = blockIdx.x & 7;
  int b = pair >> 4, h = pair & 15;
  __shared__ float sm[128 * 68];
  __shared__ float xv[128 * 68];
  int t = threadIdx.x;
  int m = t >> 2, dg = t & 3;
  float acc[16] = {};
  float nacc = 0.f;
  for (int s = 0; s < 8; ++s) {
    int bn0 = b * 8192 + chunk * 1024 + s * 128;
    for (int jj = 0; jj < 8; ++jj) {
      int idx4 = t + 256 * jj; int row = idx4 >> 4, c4 = (idx4 & 15) * 4;
      int g = (bn0 + row) * 2048 + h * 64 + c4;
      *(float4*)&sm[row * 68 + c4] = *(const float4*)&S[g];
      *(float4*)&xv[row * 68 + c4] = *(const float4*)&S[g + 1024];
    }
    __syncthreads();
    if (t < 128) {
      float tt = T[(bn0 + t) * 16 + h];
      float inv = 1.f / tt;
      float* row = &sm[t * 68];
      float mx = -1e30f;
      for (int mm = 0; mm < 64; ++mm) mx = fmaxf(mx, row[mm]);
      float sum = 0.f;
      for (int mm = 0; mm < 64; ++mm) { float e = expf((row[mm] - mx) * inv); row[mm] = e; sum += e; }
      float sinv = 1.f / sum;
      for (int mm = 0; mm < 64; ++mm) row[mm] *= sinv;
    }
    __syncthreads();
    for (int jj = 0; jj < 8; ++jj) {      // write weights back in place
      int idx4 = t + 256 * jj; int row = idx4 >> 4, c4 = (idx4 & 15) * 4;
      int g = (bn0 + row) * 2048 + h * 64 + c4;
      *(float4*)&S[g] = *(const float4*)&sm[row * 68 + c4];
    }
    for (int n = 0; n < 128; ++n) {       // token += w ⊗ xv
      float w = sm[n * 68 + m];
      if (dg == 0) nacc += w;
      const float* xr = &xv[n * 68 + dg * 16];
      #pragma unroll
      for (int q = 0; q < 4; ++q) {
        float4 v = *(const float4*)&xr[q * 4];
        acc[q * 4 + 0] = fmaf(w, v.x, acc[q * 4 + 0]);
        acc[q * 4 + 1] = fmaf(w, v.y, acc[q * 4 + 1]);
        acc[q * 4 + 2] = fmaf(w, v.z, acc[q * 4 + 2]);
        acc[q * 4 + 3] = fmaf(w, v.w, acc[q * 4 + 3]);
      }
    }
    __syncthreads();
  }
  int tb = pair * 4096 + m * 64 + dg * 16;
  for (int q = 0; q < 16; ++q) atomicAdd(&token[tb + q], acc[q]);
  if (dg == 0) atomicAdd(&norm[pair * 64 + m], nacc);
}

// ------------- stage C: tiny per-(b,h) qkv/attn -> out_slice_token -----------
__global__ __launch_bounds__(256) void k_stagec(const float* __restrict__ token,
                                                const float* __restrict__ norm,
                                                const float* __restrict__ proj,
                                                float* __restrict__ ost) {
  int pair = blockIdx.x; int h = pair & 15;
  __shared__ float st[64 * 68];
  __shared__ float qk[64 * 196];
  int t = threadIdx.x;
  for (int j = 0; j < 16; ++j) {
    int idx = t + 256 * j; int m = idx >> 6, d = idx & 63;
    st[m * 68 + d] = token[pair * 4096 + idx] / (norm[pair * 64 + m] + 1e-5f);
  }
  __syncthreads();
  for (int idx = t; idx < 64 * 192; idx += 256) {
    int m = idx / 192, e = idx % 192;
    float s = 0.f;
    const float* pr = &proj[h * 12288 + e];
    const float* sr = &st[m * 68];
    for (int d = 0; d < 64; ++d) s = fmaf(sr[d], pr[d * 192], s);
    qk[m * 196 + e] = s;
  }
  __syncthreads();
  if (t < 64) {
    const float* q = &qk[t * 196];
    float dots[64];
    float mx = -1e30f;
    for (int d = 0; d < 64; ++d) { dots[d] = q[d] * q[64 + d] * 0.125f; mx = fmaxf(mx, dots[d]); }
    float sum = 0.f;
    for (int d = 0; d < 64; ++d) { dots[d] = expf(dots[d] - mx); sum += dots[d]; }
    float sinv = 1.f / sum;
    for (int d = 0; d < 64; ++d) ost[pair * 4096 + t * 64 + d] = dots[d] * sinv * q[128 + d];
  }
}

// ------------- stage D: out_x[n, h*64+d] = sum_m ost[m,d] * w[m,n] -----------
__global__ __launch_bounds__(256) void k_staged(float* __restrict__ S, const float* __restrict__ ost) {
  int pair = blockIdx.x >> 6, chunk = blockIdx.x & 63;
  int b = pair >> 4, h = pair & 15;
  __shared__ float ws[128 * 68];
  int t = threadIdx.x;
  int bn0 = b * 8192 + chunk * 128;
  for (int jj = 0; jj < 8; ++jj) {
    int idx4 = t + 256 * jj; int row = idx4 >> 4, c4 = (idx4 & 15) * 4;
    *(float4*)&ws[row * 68 + c4] = *(const float4*)&S[(bn0 + row) * 2048 + h * 64 + c4];
  }
  int d = t & 63, ng = t >> 6;
  float o[64];
  #pragma unroll
  for (int mm = 0; mm < 64; ++mm) o[mm] = ost[pair * 4096 + mm * 64 + d];
  __syncthreads();
  for (int i = 0; i < 32; ++i) {
    int n = ng + 4 * i;
    const float* wr = &ws[n * 68];
    float s = 0.f;
    #pragma unroll
    for (int mm = 0; mm < 64; ++mm) s = fmaf(wr[mm], o[mm], s);
    S[(bn0 + n) * 2048 + 1024 + h * 64 + d] = s;
  }
}

extern "C" void kernel_launch(void* const* d_in, const int* in_sizes, int n_in,
                              void* d_out, int out_size, void* d_ws, size_t ws_size,
                              hipStream_t stream) {
  const float* x      = (const float*)d_in[0];
  // d_in[1] = c (unused by reference)
  const float* w_kv   = (const float*)d_in[2];
  const float* b_kv   = (const float*)d_in[3];
  const float* w_temp = (const float*)d_in[4];
  const float* b_temp = (const float*)d_in[5];
  const float* xq     = (const float*)d_in[6];
  const float* proj   = (const float*)d_in[7];
  const float* w_out  = (const float*)d_in[8];
  const float* b_out  = (const float*)d_in[9];
  float* out = (float*)d_out;

  float* ws    = (float*)d_ws;
  float* S     = ws;                       // [32768][2048]  scores|xv -> weights|out_x
  float* T     = S + 67108864;             // [32768][16]
  float* WBIG  = T + 524288;               // [1024][2048]
  float* BIAS1 = WBIG + 2097152;           // [2048]
  float* TOKEN = BIAS1 + 2048;             // [64 pairs][64 m][64 d] = 262144
  float* NORM  = TOKEN + 262144;           // [64 pairs][64 m]       = 4096
  float* OST   = NORM + 4096;              // [64 pairs][64 m][64 d] = 262144

  hipMemsetAsync(TOKEN, 0, (262144 + 4096) * sizeof(float), stream);
  k_acat<<<128, 256, 0, stream>>>(w_kv, xq, WBIG);
  k_copyv<<<1024, 256, 0, stream>>>(w_kv, WBIG);
  k_bias1<<<8, 256, 0, stream>>>(xq, b_kv, BIAS1);
  k_temp<<<2048, 256, 0, stream>>>(x, w_temp, b_temp, T);
  k_gemm<<<dim3(16, 256), 256, 0, stream>>>(x, 1024, WBIG, 2048, BIAS1, S, 2048, 1024);
  k_smax<<<512, 256, 0, stream>>>(S, T, TOKEN, NORM);
  k_stagec<<<64, 256, 0, stream>>>(TOKEN, NORM, proj, OST);
  k_staged<<<4096, 256, 0, stream>>>(S, OST);
  k_gemm<<<dim3(8, 256), 256, 0, stream>>>(S + 1024, 2048, w_out, 1024, b_out, out, 1024, 1024);
}

// Round 3
// 1820.184 us; speedup vs baseline: 1.6708x; 1.6708x over previous
//
#include <hip/hip_runtime.h>
#include <hip/hip_bf16.h>

// SliceAttention on MI355X — round 3: split-bf16 MFMA GEMMs (hi/lo, 3 terms)
// replacing the fp32 vector-ALU GEMMs. m97-style NT GEMM: 128x128 tile, BK=32,
// mfma_f32_16x16x32_bf16, global_load_lds width=16. Falls back to round-2 fp32
// path if ws_size is too small for the split buffers.

#define NTOK 32768   // B*N
#define HH   1024
#define NHD  16
#define DD   64

typedef short short8 __attribute__((ext_vector_type(8)));
typedef float f32x4 __attribute__((ext_vector_type(4)));

#define AS1 __attribute__((address_space(1)))
#define AS3 __attribute__((address_space(3)))

__device__ __forceinline__ void glds16(const void* g, void* l) {
  __builtin_amdgcn_global_load_lds((const AS1 void*)g, (AS3 void*)l, 16, 0, 0);
}

__device__ __forceinline__ void split1(float v, __hip_bfloat16& h, __hip_bfloat16& l) {
  h = __float2bfloat16(v);
  l = __float2bfloat16(v - __bfloat162float(h));
}

// =================== fast-path builders ===================

// AcatT rows 0..1023 of WbT: WbT[h*64+m][k] = sum_d w_kv[k][h*64+d]*xq[h][m][d]
__global__ __launch_bounds__(256) void k_acat_t(const float* __restrict__ w_kv,
                                                const float* __restrict__ xq,
                                                __hip_bfloat16* __restrict__ wbth,
                                                __hip_bfloat16* __restrict__ wbtl) {
  int hd = blockIdx.x >> 3, kt = blockIdx.x & 7, k0 = kt * 128;
  __shared__ float xqs[64 * 65];
  __shared__ float wks[128 * 65];
  int t = threadIdx.x;
  for (int j = 0; j < 16; ++j) {
    int idx = t + 256 * j; int m = idx >> 6, d = idx & 63;
    xqs[m * 65 + d] = xq[hd * 4096 + idx];
  }
  for (int j = 0; j < 32; ++j) {
    int idx = t + 256 * j; int r = idx >> 6, c = idx & 63;
    wks[r * 65 + c] = w_kv[(size_t)(k0 + r) * 2048 + hd * 64 + c];
  }
  __syncthreads();
  int m = t & 63, kg = t >> 6;
  __hip_bfloat16 hbuf[32], lbuf[32];
  for (int i = 0; i < 32; ++i) {
    int k = kg * 32 + i;
    float s = 0.f;
    #pragma unroll 8
    for (int d = 0; d < 64; ++d) s = fmaf(wks[k * 65 + d], xqs[m * 65 + d], s);
    split1(s, hbuf[i], lbuf[i]);
  }
  size_t o = (size_t)(hd * 64 + m) * 1024 + k0 + kg * 32;
  for (int i = 0; i < 32; i += 8) {
    *(uint4*)&wbth[o + i] = *(uint4*)&hbuf[i];
    *(uint4*)&wbtl[o + i] = *(uint4*)&lbuf[i];
  }
}

// transpose + split a 1024x1024 fp32 block: dst[c][r] = src[r*ld + c]
__global__ __launch_bounds__(256) void k_tsplit(const float* __restrict__ src, int ld,
                                                __hip_bfloat16* __restrict__ dh,
                                                __hip_bfloat16* __restrict__ dl) {
  __shared__ float tile[64 * 65];
  int br = blockIdx.y * 64, bc = blockIdx.x * 64;
  int t = threadIdx.x;
  for (int j = 0; j < 16; ++j) {
    int idx = t + 256 * j; int r = idx >> 6, c = idx & 63;
    tile[r * 65 + c] = src[(size_t)(br + r) * ld + bc + c];
  }
  __syncthreads();
  for (int j = 0; j < 16; ++j) {
    int idx = t + 256 * j; int c = idx >> 6, r = idx & 63;
    float v = tile[r * 65 + c];
    __hip_bfloat16 hv, lv; split1(v, hv, lv);
    size_t o = (size_t)(bc + c) * 1024 + br + r;
    dh[o] = hv; dl[o] = lv;
  }
}

// split contiguous fp32 -> bf16 hi/lo (8 elems/thread)
__global__ void k_split(const float* __restrict__ src, __hip_bfloat16* __restrict__ hi,
                        __hip_bfloat16* __restrict__ lo) {
  size_t base = ((size_t)blockIdx.x * 256 + threadIdx.x) * 8;
  float4 v0 = *(const float4*)&src[base];
  float4 v1 = *(const float4*)&src[base + 4];
  float vv[8] = {v0.x, v0.y, v0.z, v0.w, v1.x, v1.y, v1.z, v1.w};
  __hip_bfloat16 h8[8], l8[8];
  #pragma unroll
  for (int i = 0; i < 8; ++i) split1(vv[i], h8[i], l8[i]);
  *(uint4*)&hi[base] = *(uint4*)h8;
  *(uint4*)&lo[base] = *(uint4*)l8;
}

// =================== split-bf16 MFMA NT GEMM ===================
// C[M,N] = (Ah+Al)[M,1024] · (Bh+Bl)[N,1024]^T + bias[N]  (3-term)
__global__ __launch_bounds__(256) void k_mfma_bt(
    const __hip_bfloat16* __restrict__ Ah, const __hip_bfloat16* __restrict__ Al,
    const __hip_bfloat16* __restrict__ Bh, const __hip_bfloat16* __restrict__ Bl,
    const float* __restrict__ bias, float* __restrict__ C, int ldc) {
  __shared__ __align__(16) __hip_bfloat16 As[128 * 32];
  __shared__ __align__(16) __hip_bfloat16 Bs[128 * 32];
  int t = threadIdx.x;
  int w = t >> 6, lane = t & 63;
  int m0 = blockIdx.y * 128, n0 = blockIdx.x * 128;

  int g0 = w * 128 + lane, g1 = g0 + 64;           // 16B chunk ids (0..511)
  int r0 = g0 >> 2, q0 = (g0 & 3) * 8;
  int r1 = g1 >> 2, q1 = (g1 & 3) * 8;

  const __hip_bfloat16* APtr[3] = {Ah, Al, Ah};
  const __hip_bfloat16* BPtr[3] = {Bh, Bh, Bl};

  f32x4 acc[4][4];
  #pragma unroll
  for (int i = 0; i < 4; ++i)
    #pragma unroll
    for (int j = 0; j < 4; ++j) acc[i][j] = (f32x4){0.f, 0.f, 0.f, 0.f};

  int wm = (w & 1) * 64, wn = (w >> 1) * 64;
  int fm = lane & 15, fq = (lane >> 4) * 8;

  for (int seg = 0; seg < 3; ++seg) {
    const __hip_bfloat16* ga0 = APtr[seg] + (size_t)(m0 + r0) * 1024 + q0;
    const __hip_bfloat16* ga1 = APtr[seg] + (size_t)(m0 + r1) * 1024 + q1;
    const __hip_bfloat16* gb0 = BPtr[seg] + (size_t)(n0 + r0) * 1024 + q0;
    const __hip_bfloat16* gb1 = BPtr[seg] + (size_t)(n0 + r1) * 1024 + q1;
    for (int kt = 0; kt < 1024; kt += 32) {
      glds16(ga0 + kt, &As[g0 * 8]);
      glds16(ga1 + kt, &As[g1 * 8]);
      glds16(gb0 + kt, &Bs[g0 * 8]);
      glds16(gb1 + kt, &Bs[g1 * 8]);
      __syncthreads();
      short8 af[4], bf[4];
      #pragma unroll
      for (int i = 0; i < 4; ++i)
        af[i] = *(const short8*)&As[(wm + i * 16 + fm) * 32 + fq];
      #pragma unroll
      for (int j = 0; j < 4; ++j)
        bf[j] = *(const short8*)&Bs[(wn + j * 16 + fm) * 32 + fq];
      #pragma unroll
      for (int i = 0; i < 4; ++i)
        #pragma unroll
        for (int j = 0; j < 4; ++j)
          acc[i][j] = __builtin_amdgcn_mfma_f32_16x16x32_bf16(af[i], bf[j], acc[i][j], 0, 0, 0);
      __syncthreads();
    }
  }
  int cm = (lane >> 4) * 4, cn = lane & 15;
  #pragma unroll
  for (int j = 0; j < 4; ++j) {
    int col = n0 + wn + j * 16 + cn;
    float bb = bias[col];
    #pragma unroll
    for (int i = 0; i < 4; ++i) {
      int row = m0 + wm + i * 16 + cm;
      f32x4 v = acc[i][j];
      #pragma unroll
      for (int r = 0; r < 4; ++r)
        C[(size_t)(row + r) * ldc + col] = v[r] + bb;
    }
  }
}

// =================== fallback builders (round-2) ===================
__global__ __launch_bounds__(256) void k_acat(const float* __restrict__ w_kv,
                                              const float* __restrict__ xq,
                                              float* __restrict__ wbig) {
  int h = blockIdx.x >> 3, kt = blockIdx.x & 7, k0 = kt * 128;
  __shared__ float xqs[64 * 68];
  __shared__ float wks[128 * 68];
  int t = threadIdx.x;
  for (int j = 0; j < 16; ++j) {
    int idx = t + 256 * j; int m = idx >> 6, d = idx & 63;
    xqs[m * 68 + d] = xq[h * 4096 + idx];
  }
  for (int j = 0; j < 32; ++j) {
    int idx = t + 256 * j; int r = idx >> 6, c = idx & 63;
    wks[r * 68 + c] = w_kv[(k0 + r) * 2048 + h * 64 + c];
  }
  __syncthreads();
  int k = t >> 1, half = t & 1;
  float out[32];
  for (int mi = 0; mi < 32; ++mi) {
    int m = half * 32 + mi;
    float s = 0.f;
    #pragma unroll 8
    for (int d = 0; d < 64; ++d) s = fmaf(wks[k * 68 + d], xqs[m * 68 + d], s);
    out[mi] = s;
  }
  float* dst = &wbig[(k0 + k) * 2048 + h * 64 + half * 32];
  for (int mi = 0; mi < 32; mi += 4)
    *(float4*)(dst + mi) = make_float4(out[mi], out[mi + 1], out[mi + 2], out[mi + 3]);
}

__global__ void k_copyv(const float* __restrict__ w_kv, float* __restrict__ wbig) {
  int idx4 = blockIdx.x * 256 + threadIdx.x;
  int k = idx4 >> 8, j4 = idx4 & 255;
  int off = k * 2048 + 1024 + j4 * 4;
  *(float4*)(wbig + off) = *(const float4*)(w_kv + off);
}

__global__ void k_bias1(const float* __restrict__ xq, const float* __restrict__ b_kv,
                        float* __restrict__ bias1) {
  int j = blockIdx.x * 256 + threadIdx.x;
  if (j < 1024) {
    int h = j >> 6, m = j & 63;
    float s = 0.f;
    for (int d = 0; d < 64; ++d) s = fmaf(xq[h * 4096 + m * 64 + d], b_kv[h * 64 + d], s);
    bias1[j] = s;
  } else {
    bias1[j] = b_kv[j];
  }
}

__global__ __launch_bounds__(256) void k_temp(const float* __restrict__ x,
                                              const float* __restrict__ w_temp,
                                              const float* __restrict__ b_temp,
                                              float* __restrict__ T) {
  __shared__ float xs[16 * 1028];
  int t = threadIdx.x;
  int bn0 = blockIdx.x * 16;
  for (int j = 0; j < 16; ++j) {
    int idx4 = t + 256 * j; int row = idx4 >> 8, c4 = (idx4 & 255) * 4;
    *(float4*)&xs[row * 1028 + c4] = *(const float4*)&x[(bn0 + row) * 1024 + c4];
  }
  __syncthreads();
  int tok = t >> 4, j = t & 15;
  float z = b_temp[j];
  for (int k = 0; k < 1024; ++k) z = fmaf(xs[tok * 1028 + k], w_temp[k * 16 + j], z);
  float sp = fmaxf(z, 0.f) + log1pf(expf(-fabsf(z)));
  T[(bn0 + tok) * 16 + j] = 0.5f + sp;
}

__global__ __launch_bounds__(256) void k_gemm(const float* __restrict__ A, int lda,
                                              const float* __restrict__ Bm, int ldb,
                                              const float* __restrict__ bias,
                                              float* __restrict__ C, int ldc, int K) {
  __shared__ float As[8 * 132];
  __shared__ float Bs[8 * 132];
  int t = threadIdx.x;
  int m0 = blockIdx.y * 128, n0 = blockIdx.x * 128;
  int ar = t >> 1, ac = (t & 1) * 4;
  int bk = t >> 5, bc = (t & 31) * 4;
  const float* Ag = A + (size_t)(m0 + ar) * lda + ac;
  const float* Bg = Bm + (size_t)bk * ldb + n0 + bc;
  int tx = t & 15, ty = t >> 4;
  float acc[8][8] = {};
  float4 a4 = *(const float4*)Ag;
  float4 b4 = *(const float4*)Bg;
  for (int kt = 0; kt < K; kt += 8) {
    __syncthreads();
    As[(ac + 0) * 132 + ar] = a4.x;
    As[(ac + 1) * 132 + ar] = a4.y;
    As[(ac + 2) * 132 + ar] = a4.z;
    As[(ac + 3) * 132 + ar] = a4.w;
    *(float4*)&Bs[bk * 132 + bc] = b4;
    __syncthreads();
    if (kt + 8 < K) {
      a4 = *(const float4*)(Ag + kt + 8);
      b4 = *(const float4*)(Bg + (size_t)(kt + 8) * ldb);
    }
    #pragma unroll
    for (int k = 0; k < 8; ++k) {
      float av[8], bv[8];
      *(float4*)&av[0] = *(float4*)&As[k * 132 + ty * 8];
      *(float4*)&av[4] = *(float4*)&As[k * 132 + ty * 8 + 4];
      *(float4*)&bv[0] = *(float4*)&Bs[k * 132 + tx * 4];
      *(float4*)&bv[4] = *(float4*)&Bs[k * 132 + 64 + tx * 4];
      #pragma unroll
      for (int i = 0; i < 8; ++i)
        #pragma unroll
        for (int j = 0; j < 8; ++j) acc[i][j] = fmaf(av[i], bv[j], acc[i][j]);
    }
  }
  float4 bb0 = *(const float4*)&bias[n0 + tx * 4];
  float4 bb1 = *(const float4*)&bias[n0 + 64 + tx * 4];
  #pragma unroll
  for (int i = 0; i < 8; ++i) {
    float* crow = C + (size_t)(m0 + ty * 8 + i) * ldc + n0;
    float4 o0 = make_float4(acc[i][0] + bb0.x, acc[i][1] + bb0.y,
                            acc[i][2] + bb0.z, acc[i][3] + bb0.w);
    float4 o1 = make_float4(acc[i][4] + bb1.x, acc[i][5] + bb1.y,
                            acc[i][6] + bb1.z, acc[i][7] + bb1.w);
    *(float4*)&crow[tx * 4] = o0;
    *(float4*)&crow[64 + tx * 4] = o1;
  }
}

// ------------- stage B: in-place softmax over m + token/norm accumulation ----
__global__ __launch_bounds__(256) void k_smax(float* __restrict__ S, const float* __restrict__ T,
                                              float* __restrict__ token, float* __restrict__ norm) {
  int pair = blockIdx.x >> 3, chunk = blockIdx.x & 7;
  int b = pair >> 4, h = pair & 15;
  __shared__ float sm[128 * 68];
  __shared__ float xv[128 * 68];
  int t = threadIdx.x;
  int m = t >> 2, dg = t & 3;
  float acc[16] = {};
  float nacc = 0.f;
  for (int s = 0; s < 8; ++s) {
    int bn0 = b * 8192 + chunk * 1024 + s * 128;
    for (int jj = 0; jj < 8; ++jj) {
      int idx4 = t + 256 * jj; int row = idx4 >> 4, c4 = (idx4 & 15) * 4;
      int g = (bn0 + row) * 2048 + h * 64 + c4;
      *(float4*)&sm[row * 68 + c4] = *(const float4*)&S[g];
      *(float4*)&xv[row * 68 + c4] = *(const float4*)&S[g + 1024];
    }
    __syncthreads();
    if (t < 128) {
      float tt = T[(bn0 + t) * 16 + h];
      float inv = 1.f / tt;
      float* row = &sm[t * 68];
      float mx = -1e30f;
      for (int mm = 0; mm < 64; ++mm) mx = fmaxf(mx, row[mm]);
      float sum = 0.f;
      for (int mm = 0; mm < 64; ++mm) { float e = expf((row[mm] - mx) * inv); row[mm] = e; sum += e; }
      float sinv = 1.f / sum;
      for (int mm = 0; mm < 64; ++mm) row[mm] *= sinv;
    }
    __syncthreads();
    for (int jj = 0; jj < 8; ++jj) {
      int idx4 = t + 256 * jj; int row = idx4 >> 4, c4 = (idx4 & 15) * 4;
      int g = (bn0 + row) * 2048 + h * 64 + c4;
      *(float4*)&S[g] = *(const float4*)&sm[row * 68 + c4];
    }
    for (int n = 0; n < 128; ++n) {
      float w = sm[n * 68 + m];
      if (dg == 0) nacc += w;
      const float* xr = &xv[n * 68 + dg * 16];
      #pragma unroll
      for (int q = 0; q < 4; ++q) {
        float4 v = *(const float4*)&xr[q * 4];
        acc[q * 4 + 0] = fmaf(w, v.x, acc[q * 4 + 0]);
        acc[q * 4 + 1] = fmaf(w, v.y, acc[q * 4 + 1]);
        acc[q * 4 + 2] = fmaf(w, v.z, acc[q * 4 + 2]);
        acc[q * 4 + 3] = fmaf(w, v.w, acc[q * 4 + 3]);
      }
    }
    __syncthreads();
  }
  int tb = pair * 4096 + m * 64 + dg * 16;
  for (int q = 0; q < 16; ++q) atomicAdd(&token[tb + q], acc[q]);
  if (dg == 0) atomicAdd(&norm[pair * 64 + m], nacc);
}

// ------------- stage C -----------
__global__ __launch_bounds__(256) void k_stagec(const float* __restrict__ token,
                                                const float* __restrict__ norm,
                                                const float* __restrict__ proj,
                                                float* __restrict__ ost) {
  int pair = blockIdx.x; int h = pair & 15;
  __shared__ float st[64 * 68];
  __shared__ float qk[64 * 196];
  int t = threadIdx.x;
  for (int j = 0; j < 16; ++j) {
    int idx = t + 256 * j; int m = idx >> 6, d = idx & 63;
    st[m * 68 + d] = token[pair * 4096 + idx] / (norm[pair * 64 + m] + 1e-5f);
  }
  __syncthreads();
  for (int idx = t; idx < 64 * 192; idx += 256) {
    int m = idx / 192, e = idx % 192;
    float s = 0.f;
    const float* pr = &proj[h * 12288 + e];
    const float* sr = &st[m * 68];
    for (int d = 0; d < 64; ++d) s = fmaf(sr[d], pr[d * 192], s);
    qk[m * 196 + e] = s;
  }
  __syncthreads();
  if (t < 64) {
    const float* q = &qk[t * 196];
    float dots[64];
    float mx = -1e30f;
    for (int d = 0; d < 64; ++d) { dots[d] = q[d] * q[64 + d] * 0.125f; mx = fmaxf(mx, dots[d]); }
    float sum = 0.f;
    for (int d = 0; d < 64; ++d) { dots[d] = expf(dots[d] - mx); sum += dots[d]; }
    float sinv = 1.f / sum;
    for (int d = 0; d < 64; ++d) ost[pair * 4096 + t * 64 + d] = dots[d] * sinv * q[128 + d];
  }
}

// ------------- stage D (fallback: fp32 into S) -----------
__global__ __launch_bounds__(256) void k_staged(float* __restrict__ S, const float* __restrict__ ost) {
  int pair = blockIdx.x >> 6, chunk = blockIdx.x & 63;
  int b = pair >> 4, h = pair & 15;
  __shared__ float ws[128 * 68];
  int t = threadIdx.x;
  int bn0 = b * 8192 + chunk * 128;
  for (int jj = 0; jj < 8; ++jj) {
    int idx4 = t + 256 * jj; int row = idx4 >> 4, c4 = (idx4 & 15) * 4;
    *(float4*)&ws[row * 68 + c4] = *(const float4*)&S[(bn0 + row) * 2048 + h * 64 + c4];
  }
  int d = t & 63, ng = t >> 6;
  float o[64];
  #pragma unroll
  for (int mm = 0; mm < 64; ++mm) o[mm] = ost[pair * 4096 + mm * 64 + d];
  __syncthreads();
  for (int i = 0; i < 32; ++i) {
    int n = ng + 4 * i;
    const float* wr = &ws[n * 68];
    float s = 0.f;
    #pragma unroll
    for (int mm = 0; mm < 64; ++mm) s = fmaf(wr[mm], o[mm], s);
    S[(bn0 + n) * 2048 + 1024 + h * 64 + d] = s;
  }
}

// ------------- stage D (fast: bf16 hi/lo out_x, packed lda=1024) -----------
__global__ __launch_bounds__(256) void k_staged_bf(const float* __restrict__ S,
                                                   const float* __restrict__ ost,
                                                   __hip_bfloat16* __restrict__ oxh,
                                                   __hip_bfloat16* __restrict__ oxl) {
  int pair = blockIdx.x >> 6, chunk = blockIdx.x & 63;
  int b = pair >> 4, hd = pair & 15;
  __shared__ float ws[128 * 68];
  int t = threadIdx.x;
  int bn0 = b * 8192 + chunk * 128;
  for (int jj = 0; jj < 8; ++jj) {
    int idx4 = t + 256 * jj; int row = idx4 >> 4, c4 = (idx4 & 15) * 4;
    *(float4*)&ws[row * 68 + c4] = *(const float4*)&S[(bn0 + row) * 2048 + hd * 64 + c4];
  }
  int d = t & 63, ng = t >> 6;
  float o[64];
  #pragma unroll
  for (int mm = 0; mm < 64; ++mm) o[mm] = ost[pair * 4096 + mm * 64 + d];
  __syncthreads();
  for (int i = 0; i < 32; ++i) {
    int n = ng + 4 * i;
    const float* wr = &ws[n * 68];
    float s = 0.f;
    #pragma unroll
    for (int mm = 0; mm < 64; ++mm) s = fmaf(wr[mm], o[mm], s);
    __hip_bfloat16 hv, lv; split1(s, hv, lv);
    size_t oo = (size_t)(bn0 + n) * 1024 + hd * 64 + d;
    oxh[oo] = hv; oxl[oo] = lv;
  }
}

extern "C" void kernel_launch(void* const* d_in, const int* in_sizes, int n_in,
                              void* d_out, int out_size, void* d_ws, size_t ws_size,
                              hipStream_t stream) {
  const float* x      = (const float*)d_in[0];
  const float* w_kv   = (const float*)d_in[2];
  const float* b_kv   = (const float*)d_in[3];
  const float* w_temp = (const float*)d_in[4];
  const float* b_temp = (const float*)d_in[5];
  const float* xq     = (const float*)d_in[6];
  const float* proj   = (const float*)d_in[7];
  const float* w_out  = (const float*)d_in[8];
  const float* b_out  = (const float*)d_in[9];
  float* out = (float*)d_out;

  float* ws    = (float*)d_ws;
  float* S     = ws;                       // [32768][2048] fp32
  float* T     = S + 67108864;             // [32768][16]
  float* BIAS1 = T + 524288;               // [2048]
  float* TOKEN = BIAS1 + 2048;             // 262144
  float* NORM  = TOKEN + 262144;           // 4096
  float* OST   = NORM + 4096;              // 262144
  float* FEND  = OST + 262144;
  __hip_bfloat16* WbTh = (__hip_bfloat16*)FEND;   // [2048][1024]
  __hip_bfloat16* WbTl = WbTh + 2097152;          // [2048][1024]
  __hip_bfloat16* WoTh = WbTl + 2097152;          // [1024][1024]
  __hip_bfloat16* WoTl = WoTh + 1048576;          // [1024][1024]
  __hip_bfloat16* XH   = WoTl + 1048576;          // [32768][1024] (reused as out_x hi)
  __hip_bfloat16* XL   = XH + 33554432;           // [32768][1024] (reused as out_x lo)
  const size_t need_fast = 419454976ULL;          // bytes

  hipMemsetAsync(TOKEN, 0, (262144 + 4096) * sizeof(float), stream);
  k_bias1<<<8, 256, 0, stream>>>(xq, b_kv, BIAS1);
  k_temp<<<2048, 256, 0, stream>>>(x, w_temp, b_temp, T);

  if (ws_size >= need_fast) {
    // ---- fast path: split-bf16 MFMA GEMMs ----
    k_acat_t<<<128, 256, 0, stream>>>(w_kv, xq, WbTh, WbTl);
    k_tsplit<<<dim3(16, 16), 256, 0, stream>>>(w_kv + 1024, 2048,
                                               WbTh + 1048576, WbTl + 1048576);
    k_tsplit<<<dim3(16, 16), 256, 0, stream>>>(w_out, 1024, WoTh, WoTl);
    k_split<<<16384, 256, 0, stream>>>(x, XH, XL);
    k_mfma_bt<<<dim3(16, 256), 256, 0, stream>>>(XH, XL, WbTh, WbTl, BIAS1, S, 2048);
    k_smax<<<512, 256, 0, stream>>>(S, T, TOKEN, NORM);
    k_stagec<<<64, 256, 0, stream>>>(TOKEN, NORM, proj, OST);
    k_staged_bf<<<4096, 256, 0, stream>>>(S, OST, XH, XL);
    k_mfma_bt<<<dim3(8, 256), 256, 0, stream>>>(XH, XL, WoTh, WoTl, b_out, out, 1024);
  } else {
    // ---- fallback: round-2 fp32 vector GEMMs ----
    float* WBIG = (float*)WbTh;            // [1024][2048] fp32 fits in WbTh+WbTl
    k_acat<<<128, 256, 0, stream>>>(w_kv, xq, WBIG);
    k_copyv<<<1024, 256, 0, stream>>>(w_kv, WBIG);
    k_gemm<<<dim3(16, 256), 256, 0, stream>>>(x, 1024, WBIG, 2048, BIAS1, S, 2048, 1024);
    k_smax<<<512, 256, 0, stream>>>(S, T, TOKEN, NORM);
    k_stagec<<<64, 256, 0, stream>>>(TOKEN, NORM, proj, OST);
    k_staged<<<4096, 256, 0, stream>>>(S, OST);
    k_gemm<<<dim3(8, 256), 256, 0, stream>>>(S + 1024, 2048, w_out, 1024, b_out, out, 1024, 1024);
  }
}